// Round 1
// baseline (710.388 us; speedup 1.0000x reference)
//
#include <hip/hip_runtime.h>
#include <math.h>

#define BB 64
#define CC 512
#define DTT 1024
#define NNEG 53
#define MARGIN_ 0.2f
#define EPSV 1e-8f

__device__ __forceinline__ float bred_sum(float v, float* red, int tid, int nt) {
  red[tid] = v; __syncthreads();
  for (int s = nt >> 1; s > 0; s >>= 1) { if (tid < s) red[tid] += red[tid + s]; __syncthreads(); }
  float r = red[0]; __syncthreads();
  return r;
}
__device__ __forceinline__ float bred_max(float v, float* red, int tid, int nt) {
  red[tid] = v; __syncthreads();
  for (int s = nt >> 1; s > 0; s >>= 1) { if (tid < s) red[tid] = fmaxf(red[tid], red[tid + s]); __syncthreads(); }
  float r = red[0]; __syncthreads();
  return r;
}

// K1: sentence centering + l2norm -> Sn (b,c), SnT (c,b), SnSum[b]
__global__ void k_sent(const float* __restrict__ sent, float* __restrict__ Sn,
                       float* __restrict__ SnT, float* __restrict__ SnSum) {
  int b = blockIdx.x, tid = threadIdx.x;
  __shared__ float red[256];
  float x0 = sent[b * CC + tid], x1 = sent[b * CC + tid + 256];
  float mean = bred_sum(x0 + x1, red, tid, 256) * (1.0f / CC);
  float s0 = x0 - mean, s1 = x1 - mean;
  float ss = bred_sum(s0 * s0 + s1 * s1, red, tid, 256);
  float nrm = fmaxf(sqrtf(ss), EPSV);
  float n0 = s0 / nrm, n1 = s1 / nrm;
  Sn[b * CC + tid] = n0; Sn[b * CC + tid + 256] = n1;
  SnT[tid * BB + b] = n0; SnT[(tid + 256) * BB + b] = n1;
  float sn = bred_sum(n0 + n1, red, tid, 256);
  if (tid == 0) SnSum[b] = sn;
}

// KS: sim = Sn Sn^T, stable descending argsort ranks -> nn_idx, negidx, nnsim
__global__ void k_sim(const float* __restrict__ Sn, int* __restrict__ nn_idx,
                      int* __restrict__ negidx, float* __restrict__ nnsim) {
  int i = blockIdx.x, j = threadIdx.x;  // 64 threads
  float dot = 0.f;
  for (int c = 0; c < CC; ++c) dot += Sn[i * CC + c] * Sn[j * CC + c];
  __shared__ float srow[BB];
  srow[j] = dot; __syncthreads();
  float mv = srow[j];
  int rank = 0;
  for (int k = 0; k < BB; ++k) {
    float vk = srow[k];
    if (vk > mv || (vk == mv && k < j)) rank++;
  }
  if (rank == 1) { nn_idx[i] = j; nnsim[i] = mv; }
  if (rank >= 6 && rank < 59) negidx[i * NNEG + rank - 6] = j;
}

// K2: per (b,p) mean over c and centered l2 norm
__global__ void k_vstats(const float* __restrict__ videos, float* __restrict__ meanv,
                         float* __restrict__ normv) {
  int gid = blockIdx.x * 256 + threadIdx.x;  // 65536
  int b = gid >> 10, p = gid & 1023;
  const float* base = videos + (size_t)b * CC * DTT + p;
  float s = 0.f, ss = 0.f;
#pragma unroll 8
  for (int c = 0; c < CC; ++c) { float x = base[(size_t)c * DTT]; s += x; ss += x * x; }
  float mean = s * (1.0f / CC);
  float var = ss - s * mean;
  meanv[gid] = mean;
  normv[gid] = fmaxf(sqrtf(fmaxf(var, 0.f)), EPSV);
}

// K3: cross[i][j][p] = (Sn[i]*videos[j,:,p] - mean*SnSum[i]) / normv ; mask -> -inf
__global__ __launch_bounds__(256) void k_cross(const float* __restrict__ videos,
    const float* __restrict__ SnT, const float* __restrict__ SnSum,
    const float* __restrict__ meanv, const float* __restrict__ normv,
    const float* __restrict__ mask, float* __restrict__ cross) {
  int j = blockIdx.x >> 2;
  int p = ((blockIdx.x & 3) << 8) + threadIdx.x;
  const float* base = videos + (size_t)j * CC * DTT + p;
  float acc[BB];
#pragma unroll
  for (int i = 0; i < BB; ++i) acc[i] = 0.f;
  for (int c = 0; c < CC; ++c) {
    float v = base[(size_t)c * DTT];
    const float* sr = SnT + c * BB;
#pragma unroll
    for (int i = 0; i < BB; ++i) acc[i] = fmaf(sr[i], v, acc[i]);
  }
  float mb = meanv[j * DTT + p];
  float inv = 1.f / normv[j * DTT + p];
  bool masked = (mask[p] == 0.f);
#pragma unroll
  for (int i = 0; i < BB; ++i) {
    float val = (acc[i] - mb * SnSum[i]) * inv;
    if (masked) val = -INFINITY;
    cross[((size_t)i * BB + j) * DTT + p] = val;
  }
}

// K4: self_score -> pmap out, softmax -> w, wm[b] = sum w*mean
__global__ void k_softmax_w(const float* __restrict__ cross, const float* __restrict__ meanv,
                            float* __restrict__ pmap, float* __restrict__ w, float* __restrict__ wm) {
  int b = blockIdx.x, tid = threadIdx.x;
  __shared__ float red[256];
  const float* row = cross + ((size_t)b * BB + b) * DTT;
  float v[4]; float mx = -INFINITY;
#pragma unroll
  for (int q = 0; q < 4; ++q) {
    v[q] = row[q * 256 + tid];
    pmap[b * DTT + q * 256 + tid] = v[q];
    mx = fmaxf(mx, v[q]);
  }
  mx = bred_max(mx, red, tid, 256);
  float e[4]; float se = 0.f;
#pragma unroll
  for (int q = 0; q < 4; ++q) { e[q] = expf(v[q] - mx); se += e[q]; }
  se = bred_sum(se, red, tid, 256);
  float inv = 1.f / se;
  float wmacc = 0.f;
#pragma unroll
  for (int q = 0; q < 4; ++q) {
    float wv = e[q] * inv;
    w[b * DTT + q * 256 + tid] = wv;
    wmacc += wv * meanv[b * DTT + q * 256 + tid];
  }
  wmacc = bred_sum(wmacc, red, tid, 256);
  if (tid == 0) wm[b] = wmacc;
}

// K5: video_pos[b,c] = sum_p w*videos - wm[b]   (one wave per (b,c))
__global__ void k_vpos(const float* __restrict__ videos, const float* __restrict__ w,
                       const float* __restrict__ wm, float* __restrict__ vp) {
  int wid = (blockIdx.x * 256 + threadIdx.x) >> 6;
  int lane = threadIdx.x & 63;
  int b = wid >> 9, c = wid & 511;
  const float4* vb = (const float4*)(videos + (size_t)(b * CC + c) * DTT) + lane * 4;
  const float4* wb = (const float4*)(w + b * DTT) + lane * 4;
  float acc = 0.f;
#pragma unroll
  for (int q = 0; q < 4; ++q) {
    float4 x = vb[q], y = wb[q];
    acc += x.x * y.x + x.y * y.y + x.z * y.z + x.w * y.w;
  }
#pragma unroll
  for (int off = 32; off > 0; off >>= 1) acc += __shfl_xor(acc, off);
  if (lane == 0) vp[b * CC + c] = acc - wm[b];
}

// Kvpn: ||vp[b]|| and sum_c vp[b,c]
__global__ void k_vpnorm(const float* __restrict__ vp, float* __restrict__ vpn,
                         float* __restrict__ vpsum) {
  int b = blockIdx.x, tid = threadIdx.x;
  __shared__ float red[256];
  float x0 = vp[b * CC + tid], x1 = vp[b * CC + tid + 256];
  float ss = bred_sum(x0 * x0 + x1 * x1, red, tid, 256);
  float sm = bred_sum(x0 + x1, red, tid, 256);
  if (tid == 0) { vpn[b] = fmaxf(sqrtf(ss), EPSV); vpsum[b] = sm; }
}

// K6: vsim logits
__global__ void k_vsim_logits(const float* __restrict__ videos, const float* __restrict__ vp,
    const float* __restrict__ vpn, const float* __restrict__ vpsum, const int* __restrict__ nn_idx,
    const float* __restrict__ meanv, const float* __restrict__ normv, float* __restrict__ vslog) {
  int gid = blockIdx.x * 256 + threadIdx.x;
  int b = gid >> 10, p = gid & 1023;
  int nn = nn_idx[b];
  const float* base = videos + (size_t)nn * CC * DTT + p;
  const float* vpr = vp + b * CC;
  float acc = 0.f;
#pragma unroll 8
  for (int c = 0; c < CC; ++c) acc = fmaf(vpr[c], base[(size_t)c * DTT], acc);
  acc -= meanv[nn * DTT + p] * vpsum[b];
  vslog[gid] = acc / (vpn[b] * normv[nn * DTT + p]);
}

// K7: softmax(vslog) in-place -> vsim ; svp[b]=sum vs*mean[nn], svn[b]=sum (1-vs)*mask*mean[nn]
__global__ void k_softmax_vsim(float* __restrict__ vslog, const int* __restrict__ nn_idx,
    const float* __restrict__ meanv, const float* __restrict__ mask,
    float* __restrict__ svp, float* __restrict__ svn) {
  int b = blockIdx.x, tid = threadIdx.x;
  __shared__ float red[256];
  int nn = nn_idx[b];
  float v[4]; float mx = -INFINITY;
#pragma unroll
  for (int q = 0; q < 4; ++q) { v[q] = vslog[b * DTT + q * 256 + tid]; mx = fmaxf(mx, v[q]); }
  mx = bred_max(mx, red, tid, 256);
  float e[4]; float se = 0.f;
#pragma unroll
  for (int q = 0; q < 4; ++q) { e[q] = expf(v[q] - mx); se += e[q]; }
  se = bred_sum(se, red, tid, 256);
  float inv = 1.f / se;
  float sp = 0.f, sn2 = 0.f;
#pragma unroll
  for (int q = 0; q < 4; ++q) {
    int p = q * 256 + tid;
    float vs = e[q] * inv;
    vslog[b * DTT + p] = vs;
    float mm = meanv[nn * DTT + p];
    sp += vs * mm;
    sn2 += (1.f - vs) * mask[p] * mm;
  }
  sp = bred_sum(sp, red, tid, 256);
  sn2 = bred_sum(sn2, red, tid, 256);
  if (tid == 0) { svp[b] = sp; svn[b] = sn2; }
}

// K8: p_v and n_v  (one wave per (b,c))
__global__ void k_pvnv(const float* __restrict__ videos, const float* __restrict__ vsim,
    const int* __restrict__ nn_idx, const float* __restrict__ mask,
    const float* __restrict__ svp, const float* __restrict__ svn, const int* __restrict__ vn_p,
    float* __restrict__ pv, float* __restrict__ nv) {
  int wid = (blockIdx.x * 256 + threadIdx.x) >> 6;
  int lane = threadIdx.x & 63;
  int b = wid >> 9, c = wid & 511;
  int nn = nn_idx[b];
  const float4* vb = (const float4*)(videos + (size_t)(nn * CC + c) * DTT) + lane * 4;
  const float4* vs4 = (const float4*)(vsim + b * DTT) + lane * 4;
  const float4* m4 = ((const float4*)mask) + lane * 4;
  float ap = 0.f, an = 0.f;
#pragma unroll
  for (int q = 0; q < 4; ++q) {
    float4 x = vb[q], s = vs4[q], m = m4[q];
    ap += x.x * s.x + x.y * s.y + x.z * s.z + x.w * s.w;
    an += x.x * (1.f - s.x) * m.x + x.y * (1.f - s.y) * m.y + x.z * (1.f - s.z) * m.z + x.w * (1.f - s.w) * m.w;
  }
#pragma unroll
  for (int off = 32; off > 0; off >>= 1) { ap += __shfl_xor(ap, off); an += __shfl_xor(an, off); }
  if (lane == 0) {
    float kd = (float)(*vn_p - 1);
    pv[b * CC + c] = ap - svp[b];
    nv[b * CC + c] = (an - svn[b]) / kd;
  }
}

// Kvas: vas per-row mean
__global__ void k_vas(const float* __restrict__ vp, const float* __restrict__ vpn,
                      const float* __restrict__ Sn, const int* __restrict__ negidx,
                      float* __restrict__ vasrow) {
  int i = blockIdx.x, tid = threadIdx.x;  // 64 threads
  __shared__ float red[64];
  __shared__ float pos;
  float invn = 1.f / vpn[i];
  float val = 0.f;
  if (tid < NNEG) {
    int nj = negidx[i * NNEG + tid];
    float d = 0.f;
    for (int c = 0; c < CC; ++c) d += vp[i * CC + c] * Sn[nj * CC + c];
    val = d * invn;
  }
  if (tid == 63) {
    float d = 0.f;
    for (int c = 0; c < CC; ++c) d += vp[i * CC + c] * Sn[i * CC + c];
    pos = d * invn;
  }
  __syncthreads();
  float contrib = (tid < NNEG) ? fmaxf(MARGIN_ + val - pos, 0.f) : 0.f;
  float s = bred_sum(contrib, red, tid, 64);
  if (tid == 0) vasrow[i] = s / (float)NNEG;
}

// Kcrov: crov per-row (gated)
__global__ void k_crov(const float* __restrict__ vp, const float* __restrict__ vpn,
                       const float* __restrict__ pv, const float* __restrict__ nv,
                       const float* __restrict__ nnsim, float* __restrict__ crovrow) {
  int b = blockIdx.x, tid = threadIdx.x;  // 256
  __shared__ float red[256];
  float dp = 0.f, pp = 0.f, dn = 0.f, nn2 = 0.f;
  for (int c = tid; c < CC; c += 256) {
    float a = vp[b * CC + c], x = pv[b * CC + c], y = nv[b * CC + c];
    dp += a * x; pp += x * x; dn += a * y; nn2 += y * y;
  }
  dp = bred_sum(dp, red, tid, 256);
  pp = bred_sum(pp, red, tid, 256);
  dn = bred_sum(dn, red, tid, 256);
  nn2 = bred_sum(nn2, red, tid, 256);
  if (tid == 0) {
    float cosp = dp / (vpn[b] * fmaxf(sqrtf(pp), EPSV));
    float cosn = dn / (vpn[b] * fmaxf(sqrtf(nn2), EPSV));
    float crov = fmaxf(MARGIN_ + cosn - cosp, 0.f);
    crovrow[b] = (nnsim[b] > 0.9f) ? crov : 0.f;
  }
}

// K9: per (i,j): sorted top-K (desc, ties->lower idx), decay, softmax(lam*v), score
__global__ __launch_bounds__(256) void k_topk(const float* __restrict__ cross,
    const float* __restrict__ iou, const float* __restrict__ lam_p,
    const int* __restrict__ vn_p, float* __restrict__ scores) {
  int ij = blockIdx.x, tid = threadIdx.x;
  int K = *vn_p; if (K > DTT) K = DTT;
  float lam = *lam_p;
  __shared__ unsigned long long keys[DTT];
  __shared__ int ti[DTT];
  __shared__ float tv[DTT];
  __shared__ float dk[DTT];
  __shared__ float red[256];
  const float* row = cross + (size_t)ij * DTT;
  for (int p = tid; p < DTT; p += 256) {
    unsigned u = __float_as_uint(row[p]);
    unsigned mono = (u & 0x80000000u) ? ~u : (u | 0x80000000u);
    unsigned long long key = ((unsigned long long)mono << 32) | (unsigned)(~p);
    keys[p] = ~key;  // sort ascending on ~key == descending on key
  }
  __syncthreads();
  for (int k = 2; k <= DTT; k <<= 1) {
    for (int jj = k >> 1; jj > 0; jj >>= 1) {
      for (int idx = tid; idx < DTT; idx += 256) {
        int ixj = idx ^ jj;
        if (ixj > idx) {
          bool up = ((idx & k) == 0);
          unsigned long long a = keys[idx], b2 = keys[ixj];
          if ((a > b2) == up) { keys[idx] = b2; keys[ixj] = a; }
        }
      }
      __syncthreads();
    }
  }
  for (int r = tid; r < K; r += 256) {
    unsigned long long kk = ~keys[r];
    unsigned pi = ~(unsigned)kk;
    unsigned mono = (unsigned)(kk >> 32);
    unsigned u = (mono & 0x80000000u) ? (mono & 0x7FFFFFFFu) : ~mono;
    ti[r] = (int)pi;
    tv[r] = __uint_as_float(u);
  }
  __syncthreads();
  for (int r = tid; r < K; r += 256) {
    const float* irow = iou + (size_t)ti[r] * DTT;
    float d = 1.f;
    for (int m = 0; m < r; ++m) d *= (1.f - irow[ti[m]]);
    dk[r] = d;
  }
  __syncthreads();
  float mx = -INFINITY;
  for (int r = tid; r < K; r += 256) mx = fmaxf(mx, lam * tv[r]);
  mx = bred_max(mx, red, tid, 256);
  float se = 0.f, sc = 0.f;
  for (int r = tid; r < K; r += 256) {
    float e = expf(lam * tv[r] - mx);
    se += e;
    sc += e * dk[r] * tv[r];
  }
  se = bred_sum(se, red, tid, 256);
  sc = bred_sum(sc, red, tid, 256);
  if (tid == 0) scores[ij] = sc / se;
}

// Kfinal: hinge maxima + loss
__global__ void k_final(const float* __restrict__ scores, const float* __restrict__ vasrow,
                        const float* __restrict__ crovrow, float* __restrict__ out) {
  int tid = threadIdx.x;  // 64 threads
  __shared__ float sm[BB * BB];
  __shared__ float red[64];
  for (int q = tid; q < BB * BB; q += 64) sm[q] = scores[q];
  __syncthreads();
  float di = sm[tid * BB + tid];
  float rowmax = 0.f, colmax = 0.f;
  for (int k = 0; k < BB; ++k) {
    if (k != tid) {
      rowmax = fmaxf(rowmax, fmaxf(MARGIN_ + sm[tid * BB + k] - di, 0.f));
      colmax = fmaxf(colmax, fmaxf(MARGIN_ + sm[k * BB + tid] - di, 0.f));
    }
  }
  float total = bred_sum(rowmax + colmax + vasrow[tid] + crovrow[tid], red, tid, 64);
  if (tid == 0) out[0] = total * (1.0f / BB);
}

extern "C" void kernel_launch(void* const* d_in, const int* in_sizes, int n_in,
                              void* d_out, int out_size, void* d_ws, size_t ws_size,
                              hipStream_t stream) {
  const float* videos = (const float*)d_in[0];
  const float* sentences = (const float*)d_in[1];
  const float* lam = (const float*)d_in[2];
  const float* mask = (const float*)d_in[3];
  const int* valid_num = (const int*)d_in[4];
  const float* iou_maps = (const float*)d_in[5];
  float* out = (float*)d_out;
  float* pmap = out + 1;

  float* ws = (float*)d_ws;
  float* Sn = ws;                      // 32768
  float* SnT = Sn + 32768;             // 32768
  float* SnSum = SnT + 32768;          // 64
  float* meanv = SnSum + 64;           // 65536
  float* normv = meanv + 65536;        // 65536
  float* cross = normv + 65536;        // 4194304
  float* w = cross + 4194304;          // 65536
  float* wm = w + 65536;               // 64
  float* vp = wm + 64;                 // 32768
  float* vpn = vp + 32768;             // 64
  float* vpsum = vpn + 64;             // 64
  float* nnsim = vpsum + 64;           // 64
  float* vslog = nnsim + 64;           // 65536 (becomes vsim in-place)
  float* svp = vslog + 65536;          // 64
  float* svn = svp + 64;               // 64
  float* pvb = svn + 64;               // 32768
  float* nvb = pvb + 32768;            // 32768
  float* vasrow = nvb + 32768;         // 64
  float* crovrow = vasrow + 64;        // 64
  float* scores = crovrow + 64;        // 4096
  int* nn_idx = (int*)(scores + 4096); // 64
  int* negidx = nn_idx + 64;           // 3392

  k_sent<<<64, 256, 0, stream>>>(sentences, Sn, SnT, SnSum);
  k_sim<<<64, 64, 0, stream>>>(Sn, nn_idx, negidx, nnsim);
  k_vstats<<<256, 256, 0, stream>>>(videos, meanv, normv);
  k_cross<<<256, 256, 0, stream>>>(videos, SnT, SnSum, meanv, normv, mask, cross);
  k_softmax_w<<<64, 256, 0, stream>>>(cross, meanv, pmap, w, wm);
  k_vpos<<<8192, 256, 0, stream>>>(videos, w, wm, vp);
  k_vpnorm<<<64, 256, 0, stream>>>(vp, vpn, vpsum);
  k_vsim_logits<<<256, 256, 0, stream>>>(videos, vp, vpn, vpsum, nn_idx, meanv, normv, vslog);
  k_softmax_vsim<<<64, 256, 0, stream>>>(vslog, nn_idx, meanv, mask, svp, svn);
  k_pvnv<<<8192, 256, 0, stream>>>(videos, vslog, nn_idx, mask, svp, svn, valid_num, pvb, nvb);
  k_vas<<<64, 64, 0, stream>>>(vp, vpn, Sn, negidx, vasrow);
  k_crov<<<64, 256, 0, stream>>>(vp, vpn, pvb, nvb, nnsim, crovrow);
  k_topk<<<4096, 256, 0, stream>>>(cross, iou_maps, lam, valid_num, scores);
  k_final<<<1, 64, 0, stream>>>(scores, vasrow, crovrow, out);
}